// Round 13
// baseline (222.908 us; speedup 1.0000x reference)
//
#include <hip/hip_runtime.h>
#include <math.h>

#define N_ 4
#define T_ 2048
#define C_ 1024
#define H_ 16
#define D_ 64
#define NTC (N_*T_*C_)   // 8388608
#define WELEM (C_*C_)    // 1048576

typedef float f32x4  __attribute__((ext_vector_type(4)));
typedef float f32x16 __attribute__((ext_vector_type(16)));
typedef short bf16x8 __attribute__((ext_vector_type(8)));

static __device__ __forceinline__ unsigned short f2bf(float f) {
    union { float f; unsigned u; } v; v.f = f;
    unsigned r = v.u + 0x7FFFu + ((v.u >> 16) & 1u);   // RNE
    return (unsigned short)(r >> 16);
}

static __device__ __forceinline__ unsigned cvtpk(float lo, float hi) {
    unsigned r;
    asm("v_cvt_pk_bf16_f32 %0, %1, %2" : "=v"(r) : "v"(lo), "v"(hi));
    return r;
}
// v_permlane32_swap_b32 a, b — ONLY on provably distinct registers (round-5 bug).
#define PLSWAP(a, b) asm("v_permlane32_swap_b32 %0, %1" : "+v"(a), "+v"(b))

// Cross-half exchange via permlane32_swap (VALU, ~4cy) instead of
// __shfl_xor(x,32) (ds_bpermute, ~60cy + bank-conflict exposure).
// Returns a = x_lo-half on all lanes, hiout = x_hi-half on all lanes.
// The asm mov creates a value the compiler cannot coalesce with x (opaque),
// guaranteeing distinct registers for the swap (round-5 lesson).
static __device__ __forceinline__ float xhalf_pair(float x, float& hiout) {
    float a = x, b;
    asm("v_mov_b32 %0, %1" : "=v"(b) : "v"(a));
    asm("v_permlane32_swap_b32 %0, %1" : "+v"(a), "+v"(b));
    hiout = b;
    return a;
}

#define GLDS16(gptr, lptr) \
    __builtin_amdgcn_global_load_lds((const __attribute__((address_space(1))) void*)(gptr), \
                                     (__attribute__((address_space(3))) void*)(lptr), 16, 0, 0)

// ---------------------------------------------------------------------------
// Merged fp32 -> bf16 cast: x (NTC elems) then Wq|Wk|Wv|Wo (4*WELEM) into the
// contiguous x_bf|w_bf workspace region. One dispatch, 8 elems/thread.
// ---------------------------------------------------------------------------
__global__ __launch_bounds__(256) void cast_all(const float* __restrict__ x,
                                                const float* __restrict__ w0,
                                                const float* __restrict__ w1,
                                                const float* __restrict__ w2,
                                                const float* __restrict__ w3,
                                                unsigned short* __restrict__ dst) {
    const int i = blockIdx.x * 256 + threadIdx.x;
    const size_t e = (size_t)i * 8;            // element offset into dst
    const float* __restrict__ src;
    size_t soff;
    if (e < (size_t)NTC) {
        src = x; soff = e;
    } else {
        const size_t e2 = e - (size_t)NTC;
        const int z = (int)(e2 >> 20);         // / WELEM
        src = (z == 0) ? w0 : (z == 1) ? w1 : (z == 2) ? w2 : w3;
        soff = e2 & (WELEM - 1);
    }
    const float4 a = *(const float4*)(src + soff);
    const float4 b = *(const float4*)(src + soff + 4);
    unsigned short u[8] = {f2bf(a.x), f2bf(a.y), f2bf(a.z), f2bf(a.w),
                           f2bf(b.x), f2bf(b.y), f2bf(b.z), f2bf(b.w)};
    *(uint4*)&dst[e] = *(const uint4*)u;
}

// ---------------------------------------------------------------------------
// Shared GEMM body — m97 structure with BK=64 (round-12 win: 2x MFMA work per
// vmcnt(0)-drain, LDS 32 KB, occupancy preserved; qkv at ~1150 TF).
// LDS swizzle: 8 chunks of 16B per row; LDS[row][p] = logical[row][p^(row&7)]
// (pre-swizzled global source; read applies same XOR — rule #21 involution).
// ---------------------------------------------------------------------------
#define GEMM_BODY(Aptr, Bptr)                                                           \
    __shared__ __align__(16) unsigned short Abuf[128 * 64];                             \
    __shared__ __align__(16) unsigned short Bbuf[128 * 64];                             \
    const int tid  = threadIdx.x;                                                       \
    const int lane = tid & 63;                                                          \
    const int w    = tid >> 6;                                                          \
    const int lo   = lane & 15;                                                         \
    const int hi   = lane >> 4;                                                         \
    const int wm   = w >> 1;                                                            \
    const int wn   = w & 1;                                                             \
    const int rowBase = blockIdx.x * 128;                                               \
    const int colBase = blockIdx.y * 128;                                               \
    f32x4 acc[4][4];                                                                    \
    _Pragma("unroll")                                                                   \
    for (int i = 0; i < 4; ++i)                                                         \
        _Pragma("unroll")                                                               \
        for (int j = 0; j < 4; ++j) acc[i][j] = (f32x4)(0.f);                           \
    const unsigned short* gA[4];                                                        \
    const unsigned short* gB[4];                                                        \
    _Pragma("unroll")                                                                   \
    for (int j = 0; j < 4; ++j) {                                                       \
        const int cj = tid + 256 * j;                                                   \
        const int rr = cj >> 3;                                                         \
        const int cc = ((cj & 7) ^ (rr & 7)) * 8;                                       \
        gA[j] = (Aptr) + (size_t)(rowBase + rr) * C_ + cc;                              \
        gB[j] = (Bptr) + (size_t)(colBase + rr) * C_ + cc;                              \
    }                                                                                   \
    for (int k0 = 0; k0 < C_; k0 += 64) {                                               \
        _Pragma("unroll")                                                               \
        for (int j = 0; j < 4; ++j)                                                     \
            GLDS16(gA[j] + k0, &Abuf[(tid + 256 * j) * 8]);                             \
        _Pragma("unroll")                                                               \
        for (int j = 0; j < 4; ++j)                                                     \
            GLDS16(gB[j] + k0, &Bbuf[(tid + 256 * j) * 8]);                             \
        __syncthreads();                                                                \
        _Pragma("unroll")                                                               \
        for (int kk = 0; kk < 2; ++kk) {                                                \
            bf16x8 af[4], bfv[4];                                                       \
            _Pragma("unroll")                                                           \
            for (int mi = 0; mi < 4; ++mi) {                                            \
                const int row = wm * 64 + mi * 16 + lo;                                 \
                const int p = ((kk * 4 + hi) ^ (row & 7)) * 8;                          \
                af[mi] = *(const bf16x8*)&Abuf[row * 64 + p];                           \
            }                                                                           \
            _Pragma("unroll")                                                           \
            for (int ni = 0; ni < 4; ++ni) {                                            \
                const int row = wn * 64 + ni * 16 + lo;                                 \
                const int p = ((kk * 4 + hi) ^ (row & 7)) * 8;                          \
                bfv[ni] = *(const bf16x8*)&Bbuf[row * 64 + p];                          \
            }                                                                           \
            _Pragma("unroll")                                                           \
            for (int mi = 0; mi < 4; ++mi)                                              \
                _Pragma("unroll")                                                       \
                for (int ni = 0; ni < 4; ++ni)                                          \
                    acc[mi][ni] = __builtin_amdgcn_mfma_f32_16x16x32_bf16(af[mi],       \
                                      bfv[ni], acc[mi][ni], 0, 0, 0);                   \
        }                                                                               \
        __syncthreads();                                                                \
    }

// ---------------------------------------------------------------------------
// Fused QKV projection: grid (64, 8, 3); z = 0:Q, 1:K (bf16 [NH,T,D]),
// 2: V^T (bf16 [NH*64+d][T]). Q pre-scaled by log2e/sqrt(C).
// ---------------------------------------------------------------------------
__global__ __launch_bounds__(256) void qkv_fused(const unsigned short* __restrict__ A,
                                                 const unsigned short* __restrict__ Wall,
                                                 unsigned short* __restrict__ qkvout) {
    const int z = blockIdx.z;
    const unsigned short* __restrict__ B = Wall + (size_t)z * WELEM;
    unsigned short* __restrict__ Y = qkvout + (size_t)z * NTC;
    const float oscale = (z == 0) ? (0.03125f * 1.44269504f) : 1.0f;

    GEMM_BODY(A, B)

    if (z < 2) {
        #pragma unroll
        for (int mi = 0; mi < 4; ++mi) {
            #pragma unroll
            for (int r = 0; r < 4; ++r) {
                const int row = rowBase + wm * 64 + mi * 16 + hi * 4 + r;
                const int nn = row >> 11, tt = row & (T_ - 1);
                #pragma unroll
                for (int ni = 0; ni < 4; ++ni) {
                    const int col = colBase + wn * 64 + ni * 16 + lo;
                    Y[((size_t)((nn * H_ + (col >> 6)) * T_ + tt)) * D_ + (col & 63)] =
                        f2bf(acc[mi][ni][r] * oscale);
                }
            }
        }
    } else {
        #pragma unroll
        for (int mi = 0; mi < 4; ++mi) {
            #pragma unroll
            for (int r = 0; r < 4; ++r) {
                const int row = rowBase + wm * 64 + mi * 16 + hi * 4 + r;
                const int nn = row >> 11, tt = row & (T_ - 1);
                #pragma unroll
                for (int ni = 0; ni < 4; ++ni) {
                    const int col = colBase + wn * 64 + ni * 16 + lo;
                    Y[(size_t)((nn * 16 + (col >> 6)) * 64 + (col & 63)) * T_ + tt] =
                        f2bf(acc[mi][ni][r]);
                }
            }
        }
    }
}

// ---------------------------------------------------------------------------
// Output projection: out = A @ Wo^T + bo (fp32 out).
// ---------------------------------------------------------------------------
__global__ __launch_bounds__(256) void out_gemm(const unsigned short* __restrict__ A,
                                                const unsigned short* __restrict__ B,
                                                const float* __restrict__ bo,
                                                float* __restrict__ out) {
    GEMM_BODY(A, B)

    float bias[4];
    #pragma unroll
    for (int ni = 0; ni < 4; ++ni) bias[ni] = bo[colBase + wn * 64 + ni * 16 + lo];
    #pragma unroll
    for (int mi = 0; mi < 4; ++mi) {
        #pragma unroll
        for (int r = 0; r < 4; ++r) {
            const int row = rowBase + wm * 64 + mi * 16 + hi * 4 + r;
            #pragma unroll
            for (int ni = 0; ni < 4; ++ni) {
                const int col = colBase + wn * 64 + ni * 16 + lo;
                out[(size_t)row * C_ + col] = acc[mi][ni][r] + bias[ni];
            }
        }
    }
}

// ---------------------------------------------------------------------------
// 32x32 MFMA flash attention — round-12 core with two round-13 changes:
//  * HEAD-MAJOR grid: bid = nh*16 + (15-qtile). Consecutive blocks share one
//    head's K/V stream -> concurrent KV working set halves (16 MB vs 32 MB
//    when qtile-major put all 64 heads in flight). Round-9's scatter-ordering
//    regression showed ordering drives L2 behavior; this is the locality-
//    maximizing order. Longest-first within head preserved.
//  * Cross-half softmax reductions via permlane32_swap (xhalf_pair) instead
//    of __shfl_xor(,32)/ds_bpermute — removes an LDS round-trip (~60cy) from
//    the serial softmax chain 2x/tile and the suspected source of the 4.26M
//    SQ_LDS_BANK_CONFLICT.
// Core unchanged: (256,2), KVBLK=64, double-buffered K [k][64] + V^T [d][64k]
// via global_load_lds, XOR-pre-swizzled source (granule^(row&7)).
// mfma_f32_32x32x16_bf16 C/D: col=l&31, row=(r&3)+8*(r>>2)+4*(l>>5).
// Swapped QK^T (lane-local softmax), T12 cvt_pk+permlane PA, T13 defer-max,
// depth-5 tree reductions.
// ---------------------------------------------------------------------------
__global__ __launch_bounds__(256, 2) void attn_mfma(const unsigned short* __restrict__ qg,
                                                    const unsigned short* __restrict__ kg,
                                                    const unsigned short* __restrict__ vtg,
                                                    unsigned short* __restrict__ ob) {
    __shared__ __align__(16) unsigned short Kt[2][64 * 64];
    __shared__ __align__(16) unsigned short Vt[2][64 * 64];

    const int tid  = threadIdx.x;
    const int w    = tid >> 6;
    const int lane = tid & 63;
    const int ql   = lane & 31;      // this lane's q-row (and d-col in PV)
    const int h    = lane >> 5;
    const int bid  = blockIdx.x;
    const int qtile = 15 - (bid & 15);           // head-major, longest-first in head
    const int nh   = bid >> 4;
    const int qb   = qtile * 128;
    const size_t base  = (size_t)nh * (T_ * D_);
    const size_t vbase = (size_t)nh * 64 * T_;
    const int qrow0 = qb + w * 32;

    // Q B-fragments (held whole kernel); Q pre-scaled by log2e/sqrt(C).
    bf16x8 qf[4];
    #pragma unroll
    for (int dsl = 0; dsl < 4; ++dsl)
        qf[dsl] = *(const bf16x8*)(qg + base + (size_t)(qrow0 + ql) * D_ + dsl * 16 + h * 8);

    f32x16 acc0 = (f32x16)(0.f), acc1 = (f32x16)(0.f);
    float mrun = -INFINITY, lrun = 0.f;

    const int mynkt  = (qrow0 >> 6) + 1;
    const int nktmax = (qb >> 6) + 2;
    const int csubdiag = (w & 1) + 1;

    // staging constants: thread handles 16B chunks i0, i1 of each tile
    const int i0 = tid, i1 = tid + 256;
    const int kr0 = i0 >> 3, kc0 = ((i0 & 7) ^ (kr0 & 7)) * 8;
    const int kr1 = i1 >> 3, kc1 = ((i1 & 7) ^ (kr1 & 7)) * 8;

    #define STAGE(kt_, buf_)                                                            \
        do {                                                                            \
            const int kb_ = (kt_) * 64;                                                 \
            GLDS16(kg + base + (size_t)(kb_ + kr0) * D_ + kc0, &Kt[buf_][i0 * 8]);      \
            GLDS16(kg + base + (size_t)(kb_ + kr1) * D_ + kc1, &Kt[buf_][i1 * 8]);      \
            GLDS16(vtg + vbase + (size_t)kr0 * T_ + kb_ + kc0, &Vt[buf_][i0 * 8]);      \
            GLDS16(vtg + vbase + (size_t)kr1 * T_ + kb_ + kc1, &Vt[buf_][i1 * 8]);      \
        } while (0)

    STAGE(0, 0);
    __syncthreads();
    int cur = 0;

    for (int kt = 0; kt < nktmax; ++kt) {
        if (kt + 1 < nktmax) STAGE(kt + 1, cur ^ 1);

        if (kt < mynkt) {
            const bool diag = (kt == mynkt - 1);
            const int csub = diag ? csubdiag : 2;
            const unsigned short* Kb = Kt[cur];
            const unsigned short* Vb = Vt[cur];

            // ---- S^T = K * Q^T ----
            f32x16 s0, s1;
            __builtin_amdgcn_s_setprio(1);
            {
                f32x16 z = (f32x16)(0.f);
                #pragma unroll
                for (int dsl = 0; dsl < 4; ++dsl) {
                    const bf16x8 ka = *(const bf16x8*)&Kb[ql * 64 + ((dsl * 2 + h) ^ (ql & 7)) * 8];
                    z = __builtin_amdgcn_mfma_f32_32x32x16_bf16(ka, qf[dsl], z, 0, 0, 0);
                }
                s0 = z;
            }
            if (csub > 1) {
                f32x16 z = (f32x16)(0.f);
                #pragma unroll
                for (int dsl = 0; dsl < 4; ++dsl) {
                    const bf16x8 ka = *(const bf16x8*)&Kb[(32 + ql) * 64 + ((dsl * 2 + h) ^ (ql & 7)) * 8];
                    z = __builtin_amdgcn_mfma_f32_32x32x16_bf16(ka, qf[dsl], z, 0, 0, 0);
                }
                s1 = z;
            }
            __builtin_amdgcn_s_setprio(0);

            // ---- causal mask (diag tile: mask last computed subtile) ----
            if (diag) {
                #pragma unroll
                for (int r = 0; r < 16; ++r) {
                    const int rc = (r & 3) + 8 * (r >> 2) + 4 * h;
                    if (csub == 1) { if (rc > ql) s0[r] = -1e30f; }
                    else           { if (rc > ql) s1[r] = -1e30f; }
                }
            }

            // ---- row max: depth-5 tree + permlane cross-half ----
            float tm;
            {
                float t[8];
                if (csub > 1) {
                    #pragma unroll
                    for (int r = 0; r < 8; ++r)
                        t[r] = fmaxf(fmaxf(s0[2 * r], s0[2 * r + 1]),
                                     fmaxf(s1[2 * r], s1[2 * r + 1]));
                } else {
                    #pragma unroll
                    for (int r = 0; r < 8; ++r) t[r] = fmaxf(s0[2 * r], s0[2 * r + 1]);
                }
                t[0] = fmaxf(t[0], t[4]); t[1] = fmaxf(t[1], t[5]);
                t[2] = fmaxf(t[2], t[6]); t[3] = fmaxf(t[3], t[7]);
                t[0] = fmaxf(t[0], t[2]); t[1] = fmaxf(t[1], t[3]);
                tm = fmaxf(t[0], t[1]);
                float tl, th;
                tl = xhalf_pair(tm, th);
                tm = fmaxf(tl, th);
            }

            // ---- defer-max rescale (T13, THR=8, log2 domain) ----
            if (!__all(tm <= mrun + 8.f)) {
                const float mnew = fmaxf(mrun, tm);
                const float fsc = exp2f(mrun - mnew);
                mrun = mnew;
                lrun *= fsc;
                #pragma unroll
                for (int r = 0; r < 16; ++r) {
                    const float f = __shfl(fsc, (r & 3) + 8 * (r >> 2) + 4 * h);
                    acc0[r] *= f; acc1[r] *= f;
                }
            }

            // ---- P = exp2(S - m); psum via depth-5 tree + permlane ----
            #pragma unroll
            for (int r = 0; r < 16; ++r) s0[r] = exp2f(s0[r] - mrun);
            if (csub > 1) {
                #pragma unroll
                for (int r = 0; r < 16; ++r) s1[r] = exp2f(s1[r] - mrun);
            }
            {
                float t[8];
                if (csub > 1) {
                    #pragma unroll
                    for (int r = 0; r < 8; ++r)
                        t[r] = (s0[2 * r] + s0[2 * r + 1]) + (s1[2 * r] + s1[2 * r + 1]);
                } else {
                    #pragma unroll
                    for (int r = 0; r < 8; ++r) t[r] = s0[2 * r] + s0[2 * r + 1];
                }
                t[0] += t[4]; t[1] += t[5]; t[2] += t[6]; t[3] += t[7];
                t[0] += t[2]; t[1] += t[3];
                float psum = t[0] + t[1];
                float pl, ph;
                pl = xhalf_pair(psum, ph);
                lrun += pl + ph;
            }

            // ---- PA fragments in-register (T12) ----
            bf16x8 pa[4];
            #pragma unroll
            for (int a = 0; a < 2; ++a) {
                if (a < csub) {
                    #pragma unroll
                    for (int b = 0; b < 2; ++b) {
                        const f32x16& P = a ? s1 : s0;
                        unsigned w0 = cvtpk(P[8 * b + 0], P[8 * b + 1]);
                        unsigned w1 = cvtpk(P[8 * b + 2], P[8 * b + 3]);
                        unsigned w2 = cvtpk(P[8 * b + 4], P[8 * b + 5]);
                        unsigned w3 = cvtpk(P[8 * b + 6], P[8 * b + 7]);
                        PLSWAP(w0, w2);   // distinct registers: safe
                        PLSWAP(w1, w3);
                        unsigned wd[4] = {w0, w1, w2, w3};
                        pa[2 * a + b] = *(bf16x8*)wd;
                    }
                }
            }

            // ---- O += P V ----
            __builtin_amdgcn_s_setprio(1);
            #pragma unroll
            for (int ks = 0; ks < 4; ++ks) {
                if (ks < 2 * csub) {
                    const bf16x8 vf0 = *(const bf16x8*)&Vb[ql * 64 + ((ks * 2 + h) ^ (ql & 7)) * 8];
                    const bf16x8 vf1 = *(const bf16x8*)&Vb[(32 + ql) * 64 + ((ks * 2 + h) ^ (ql & 7)) * 8];
                    acc0 = __builtin_amdgcn_mfma_f32_32x32x16_bf16(pa[ks], vf0, acc0, 0, 0, 0);
                    acc1 = __builtin_amdgcn_mfma_f32_32x32x16_bf16(pa[ks], vf1, acc1, 0, 0, 0);
                }
            }
            __builtin_amdgcn_s_setprio(0);
        }
        __syncthreads();
        cur ^= 1;
    }

    // ---- epilogue: normalize, write bf16 [N*T, C] ----
    const float linv = 1.f / lrun;
    const int nn = nh >> 4, hh = nh & 15;
    #pragma unroll
    for (int r = 0; r < 16; ++r) {
        const int rc = (r & 3) + 8 * (r >> 2) + 4 * h;
        const float li = __shfl(linv, rc);
        const size_t rb = (size_t)(nn * T_ + qrow0 + rc) * C_ + hh * 64;
        ob[rb + ql]      = f2bf(acc0[r] * li);
        ob[rb + 32 + ql] = f2bf(acc1[r] * li);
    }
    #undef STAGE
}

// ---------------------------------------------------------------------------
extern "C" void kernel_launch(void* const* d_in, const int* in_sizes, int n_in,
                              void* d_out, int out_size, void* d_ws, size_t ws_size,
                              hipStream_t stream) {
    const float* x  = (const float*)d_in[0];
    const float* Wq = (const float*)d_in[1];
    const float* Wk = (const float*)d_in[2];
    const float* Wv = (const float*)d_in[3];
    const float* Wo = (const float*)d_in[4];
    const float* bo = (const float*)d_in[5];
    float* out = (float*)d_out;

    unsigned short* ws = (unsigned short*)d_ws;
    unsigned short* x_bf   = ws;                         // NTC
    unsigned short* w_bf   = x_bf + (size_t)NTC;         // 4*WELEM (contiguous after x_bf)
    unsigned short* qkv_bf = w_bf + (size_t)4 * WELEM;   // Q | K | V^T, NTC each
    unsigned short* a_bf   = qkv_bf + (size_t)3 * NTC;

    // one merged cast dispatch: x_bf | w_bf region is contiguous
    cast_all<<<(NTC + 4 * WELEM) / (8 * 256), 256, 0, stream>>>(x, Wq, Wk, Wv, Wo, x_bf);

    dim3 gq(N_ * T_ / 128, C_ / 128, 3);
    qkv_fused<<<gq, 256, 0, stream>>>(x_bf, w_bf, qkv_bf);

    attn_mfma<<<(T_ / 128) * (N_ * H_), 256, 0, stream>>>(
        qkv_bf, qkv_bf + (size_t)NTC, qkv_bf + (size_t)2 * NTC, a_bf);

    dim3 gg(N_ * T_ / 128, C_ / 128);
    out_gemm<<<gg, 256, 0, stream>>>(a_bf, w_bf + 3 * (size_t)WELEM, bo, out);
}

// Round 14
// 164.468 us; speedup vs baseline: 1.3553x; 1.3553x over previous
//
#include <hip/hip_runtime.h>
#include <math.h>

#define N_ 4
#define T_ 2048
#define C_ 1024
#define H_ 16
#define D_ 64
#define NTC (N_*T_*C_)   // 8388608
#define WELEM (C_*C_)    // 1048576

typedef float f32x4  __attribute__((ext_vector_type(4)));
typedef float f32x16 __attribute__((ext_vector_type(16)));
typedef short bf16x8 __attribute__((ext_vector_type(8)));

static __device__ __forceinline__ unsigned short f2bf(float f) {
    union { float f; unsigned u; } v; v.f = f;
    unsigned r = v.u + 0x7FFFu + ((v.u >> 16) & 1u);   // RNE
    return (unsigned short)(r >> 16);
}

static __device__ __forceinline__ unsigned cvtpk(float lo, float hi) {
    unsigned r;
    asm("v_cvt_pk_bf16_f32 %0, %1, %2" : "=v"(r) : "v"(lo), "v"(hi));
    return r;
}
// v_permlane32_swap_b32 a, b — ONLY on provably distinct registers (round-5 bug).
#define PLSWAP(a, b) asm("v_permlane32_swap_b32 %0, %1" : "+v"(a), "+v"(b))

// Cross-half exchange via permlane32_swap (VALU) instead of __shfl_xor(x,32)
// (ds_bpermute). Correctness proven in round 13 (absmax identical). The asm
// mov creates a value the compiler cannot coalesce with x (opaque), so the
// swap operands are guaranteed distinct registers (round-5 lesson).
static __device__ __forceinline__ float xhalf_pair(float x, float& hiout) {
    float a = x, b;
    asm("v_mov_b32 %0, %1" : "=v"(b) : "v"(a));
    asm("v_permlane32_swap_b32 %0, %1" : "+v"(a), "+v"(b));
    hiout = b;
    return a;
}

#define GLDS16(gptr, lptr) \
    __builtin_amdgcn_global_load_lds((const __attribute__((address_space(1))) void*)(gptr), \
                                     (__attribute__((address_space(3))) void*)(lptr), 16, 0, 0)

// ---------------------------------------------------------------------------
// Merged fp32 -> bf16 cast: x (NTC elems) then Wq|Wk|Wv|Wo (4*WELEM) into the
// contiguous x_bf|w_bf workspace region. One dispatch, 8 elems/thread.
// ---------------------------------------------------------------------------
__global__ __launch_bounds__(256) void cast_all(const float* __restrict__ x,
                                                const float* __restrict__ w0,
                                                const float* __restrict__ w1,
                                                const float* __restrict__ w2,
                                                const float* __restrict__ w3,
                                                unsigned short* __restrict__ dst) {
    const int i = blockIdx.x * 256 + threadIdx.x;
    const size_t e = (size_t)i * 8;            // element offset into dst
    const float* __restrict__ src;
    size_t soff;
    if (e < (size_t)NTC) {
        src = x; soff = e;
    } else {
        const size_t e2 = e - (size_t)NTC;
        const int z = (int)(e2 >> 20);         // / WELEM
        src = (z == 0) ? w0 : (z == 1) ? w1 : (z == 2) ? w2 : w3;
        soff = e2 & (WELEM - 1);
    }
    const float4 a = *(const float4*)(src + soff);
    const float4 b = *(const float4*)(src + soff + 4);
    unsigned short u[8] = {f2bf(a.x), f2bf(a.y), f2bf(a.z), f2bf(a.w),
                           f2bf(b.x), f2bf(b.y), f2bf(b.z), f2bf(b.w)};
    *(uint4*)&dst[e] = *(const uint4*)u;
}

// ---------------------------------------------------------------------------
// Shared GEMM body — m97 structure with BK=64 (round-12 win: 2x MFMA work per
// vmcnt(0)-drain, LDS 32 KB, occupancy preserved; qkv at ~1150 TF).
// LDS swizzle: 8 chunks of 16B per row; LDS[row][p] = logical[row][p^(row&7)]
// (pre-swizzled global source; read applies same XOR — rule #21 involution).
// ---------------------------------------------------------------------------
#define GEMM_BODY(Aptr, Bptr)                                                           \
    __shared__ __align__(16) unsigned short Abuf[128 * 64];                             \
    __shared__ __align__(16) unsigned short Bbuf[128 * 64];                             \
    const int tid  = threadIdx.x;                                                       \
    const int lane = tid & 63;                                                          \
    const int w    = tid >> 6;                                                          \
    const int lo   = lane & 15;                                                         \
    const int hi   = lane >> 4;                                                         \
    const int wm   = w >> 1;                                                            \
    const int wn   = w & 1;                                                             \
    const int rowBase = blockIdx.x * 128;                                               \
    const int colBase = blockIdx.y * 128;                                               \
    f32x4 acc[4][4];                                                                    \
    _Pragma("unroll")                                                                   \
    for (int i = 0; i < 4; ++i)                                                         \
        _Pragma("unroll")                                                               \
        for (int j = 0; j < 4; ++j) acc[i][j] = (f32x4)(0.f);                           \
    const unsigned short* gA[4];                                                        \
    const unsigned short* gB[4];                                                        \
    _Pragma("unroll")                                                                   \
    for (int j = 0; j < 4; ++j) {                                                       \
        const int cj = tid + 256 * j;                                                   \
        const int rr = cj >> 3;                                                         \
        const int cc = ((cj & 7) ^ (rr & 7)) * 8;                                       \
        gA[j] = (Aptr) + (size_t)(rowBase + rr) * C_ + cc;                              \
        gB[j] = (Bptr) + (size_t)(colBase + rr) * C_ + cc;                              \
    }                                                                                   \
    for (int k0 = 0; k0 < C_; k0 += 64) {                                               \
        _Pragma("unroll")                                                               \
        for (int j = 0; j < 4; ++j)                                                     \
            GLDS16(gA[j] + k0, &Abuf[(tid + 256 * j) * 8]);                             \
        _Pragma("unroll")                                                               \
        for (int j = 0; j < 4; ++j)                                                     \
            GLDS16(gB[j] + k0, &Bbuf[(tid + 256 * j) * 8]);                             \
        __syncthreads();                                                                \
        _Pragma("unroll")                                                               \
        for (int kk = 0; kk < 2; ++kk) {                                                \
            bf16x8 af[4], bfv[4];                                                       \
            _Pragma("unroll")                                                           \
            for (int mi = 0; mi < 4; ++mi) {                                            \
                const int row = wm * 64 + mi * 16 + lo;                                 \
                const int p = ((kk * 4 + hi) ^ (row & 7)) * 8;                          \
                af[mi] = *(const bf16x8*)&Abuf[row * 64 + p];                           \
            }                                                                           \
            _Pragma("unroll")                                                           \
            for (int ni = 0; ni < 4; ++ni) {                                            \
                const int row = wn * 64 + ni * 16 + lo;                                 \
                const int p = ((kk * 4 + hi) ^ (row & 7)) * 8;                          \
                bfv[ni] = *(const bf16x8*)&Bbuf[row * 64 + p];                          \
            }                                                                           \
            _Pragma("unroll")                                                           \
            for (int mi = 0; mi < 4; ++mi)                                              \
                _Pragma("unroll")                                                       \
                for (int ni = 0; ni < 4; ++ni)                                          \
                    acc[mi][ni] = __builtin_amdgcn_mfma_f32_16x16x32_bf16(af[mi],       \
                                      bfv[ni], acc[mi][ni], 0, 0, 0);                   \
        }                                                                               \
        __syncthreads();                                                                \
    }

// ---------------------------------------------------------------------------
// Fused QKV projection: grid (64, 8, 3); z = 0:Q, 1:K (bf16 [NH,T,D]),
// 2: V^T (bf16 [NH*64+d][T]). Q pre-scaled by log2e/sqrt(C).
// ---------------------------------------------------------------------------
__global__ __launch_bounds__(256) void qkv_fused(const unsigned short* __restrict__ A,
                                                 const unsigned short* __restrict__ Wall,
                                                 unsigned short* __restrict__ qkvout) {
    const int z = blockIdx.z;
    const unsigned short* __restrict__ B = Wall + (size_t)z * WELEM;
    unsigned short* __restrict__ Y = qkvout + (size_t)z * NTC;
    const float oscale = (z == 0) ? (0.03125f * 1.44269504f) : 1.0f;

    GEMM_BODY(A, B)

    if (z < 2) {
        #pragma unroll
        for (int mi = 0; mi < 4; ++mi) {
            #pragma unroll
            for (int r = 0; r < 4; ++r) {
                const int row = rowBase + wm * 64 + mi * 16 + hi * 4 + r;
                const int nn = row >> 11, tt = row & (T_ - 1);
                #pragma unroll
                for (int ni = 0; ni < 4; ++ni) {
                    const int col = colBase + wn * 64 + ni * 16 + lo;
                    Y[((size_t)((nn * H_ + (col >> 6)) * T_ + tt)) * D_ + (col & 63)] =
                        f2bf(acc[mi][ni][r] * oscale);
                }
            }
        }
    } else {
        #pragma unroll
        for (int mi = 0; mi < 4; ++mi) {
            #pragma unroll
            for (int r = 0; r < 4; ++r) {
                const int row = rowBase + wm * 64 + mi * 16 + hi * 4 + r;
                const int nn = row >> 11, tt = row & (T_ - 1);
                #pragma unroll
                for (int ni = 0; ni < 4; ++ni) {
                    const int col = colBase + wn * 64 + ni * 16 + lo;
                    Y[(size_t)((nn * 16 + (col >> 6)) * 64 + (col & 63)) * T_ + tt] =
                        f2bf(acc[mi][ni][r]);
                }
            }
        }
    }
}

// ---------------------------------------------------------------------------
// Output projection: out = A @ Wo^T + bo (fp32 out).
// ---------------------------------------------------------------------------
__global__ __launch_bounds__(256) void out_gemm(const unsigned short* __restrict__ A,
                                                const unsigned short* __restrict__ B,
                                                const float* __restrict__ bo,
                                                float* __restrict__ out) {
    GEMM_BODY(A, B)

    float bias[4];
    #pragma unroll
    for (int ni = 0; ni < 4; ++ni) bias[ni] = bo[colBase + wn * 64 + ni * 16 + lo];
    #pragma unroll
    for (int mi = 0; mi < 4; ++mi) {
        #pragma unroll
        for (int r = 0; r < 4; ++r) {
            const int row = rowBase + wm * 64 + mi * 16 + hi * 4 + r;
            #pragma unroll
            for (int ni = 0; ni < 4; ++ni) {
                const int col = colBase + wn * 64 + ni * 16 + lo;
                out[(size_t)row * C_ + col] = acc[mi][ni][r] + bias[ni];
            }
        }
    }
}

// ---------------------------------------------------------------------------
// 32x32 MFMA flash attention — round-12 configuration (qtile-major grid
// RESTORED; round-13's head-major grid desynchronized the per-head K/V
// streaming fronts -> FETCH 29->111 MB, attn 84->144 µs). qtile-major keeps
// all heads' long blocks in lockstep so L2 holds a narrow moving window.
// Kept from round 13: xhalf_pair cross-half reduction (correctness proven;
// VALU permlane vs ds_bpermute on the serial softmax chain).
// Core: (256,2), KVBLK=64, double-buffered K [k][64] + V^T [d][64k] via
// global_load_lds, XOR-pre-swizzled source (granule^(row&7)).
// mfma_f32_32x32x16_bf16 C/D: col=l&31, row=(r&3)+8*(r>>2)+4*(l>>5).
// Swapped QK^T (lane-local softmax), T12 cvt_pk+permlane PA, T13 defer-max,
// depth-5 tree reductions.
// ---------------------------------------------------------------------------
__global__ __launch_bounds__(256, 2) void attn_mfma(const unsigned short* __restrict__ qg,
                                                    const unsigned short* __restrict__ kg,
                                                    const unsigned short* __restrict__ vtg,
                                                    unsigned short* __restrict__ ob) {
    __shared__ __align__(16) unsigned short Kt[2][64 * 64];
    __shared__ __align__(16) unsigned short Vt[2][64 * 64];

    const int tid  = threadIdx.x;
    const int w    = tid >> 6;
    const int lane = tid & 63;
    const int ql   = lane & 31;      // this lane's q-row (and d-col in PV)
    const int h    = lane >> 5;
    const int bid  = blockIdx.x;
    const int qtile = 15 - (bid >> 6);           // qtile-major, longest first
    const int nh   = bid & 63;
    const int qb   = qtile * 128;
    const size_t base  = (size_t)nh * (T_ * D_);
    const size_t vbase = (size_t)nh * 64 * T_;
    const int qrow0 = qb + w * 32;

    // Q B-fragments (held whole kernel); Q pre-scaled by log2e/sqrt(C).
    bf16x8 qf[4];
    #pragma unroll
    for (int dsl = 0; dsl < 4; ++dsl)
        qf[dsl] = *(const bf16x8*)(qg + base + (size_t)(qrow0 + ql) * D_ + dsl * 16 + h * 8);

    f32x16 acc0 = (f32x16)(0.f), acc1 = (f32x16)(0.f);
    float mrun = -INFINITY, lrun = 0.f;

    const int mynkt  = (qrow0 >> 6) + 1;
    const int nktmax = (qb >> 6) + 2;
    const int csubdiag = (w & 1) + 1;

    // staging constants: thread handles 16B chunks i0, i1 of each tile
    const int i0 = tid, i1 = tid + 256;
    const int kr0 = i0 >> 3, kc0 = ((i0 & 7) ^ (kr0 & 7)) * 8;
    const int kr1 = i1 >> 3, kc1 = ((i1 & 7) ^ (kr1 & 7)) * 8;

    #define STAGE(kt_, buf_)                                                            \
        do {                                                                            \
            const int kb_ = (kt_) * 64;                                                 \
            GLDS16(kg + base + (size_t)(kb_ + kr0) * D_ + kc0, &Kt[buf_][i0 * 8]);      \
            GLDS16(kg + base + (size_t)(kb_ + kr1) * D_ + kc1, &Kt[buf_][i1 * 8]);      \
            GLDS16(vtg + vbase + (size_t)kr0 * T_ + kb_ + kc0, &Vt[buf_][i0 * 8]);      \
            GLDS16(vtg + vbase + (size_t)kr1 * T_ + kb_ + kc1, &Vt[buf_][i1 * 8]);      \
        } while (0)

    STAGE(0, 0);
    __syncthreads();
    int cur = 0;

    for (int kt = 0; kt < nktmax; ++kt) {
        if (kt + 1 < nktmax) STAGE(kt + 1, cur ^ 1);

        if (kt < mynkt) {
            const bool diag = (kt == mynkt - 1);
            const int csub = diag ? csubdiag : 2;
            const unsigned short* Kb = Kt[cur];
            const unsigned short* Vb = Vt[cur];

            // ---- S^T = K * Q^T ----
            f32x16 s0, s1;
            __builtin_amdgcn_s_setprio(1);
            {
                f32x16 z = (f32x16)(0.f);
                #pragma unroll
                for (int dsl = 0; dsl < 4; ++dsl) {
                    const bf16x8 ka = *(const bf16x8*)&Kb[ql * 64 + ((dsl * 2 + h) ^ (ql & 7)) * 8];
                    z = __builtin_amdgcn_mfma_f32_32x32x16_bf16(ka, qf[dsl], z, 0, 0, 0);
                }
                s0 = z;
            }
            if (csub > 1) {
                f32x16 z = (f32x16)(0.f);
                #pragma unroll
                for (int dsl = 0; dsl < 4; ++dsl) {
                    const bf16x8 ka = *(const bf16x8*)&Kb[(32 + ql) * 64 + ((dsl * 2 + h) ^ (ql & 7)) * 8];
                    z = __builtin_amdgcn_mfma_f32_32x32x16_bf16(ka, qf[dsl], z, 0, 0, 0);
                }
                s1 = z;
            }
            __builtin_amdgcn_s_setprio(0);

            // ---- causal mask (diag tile: mask last computed subtile) ----
            if (diag) {
                #pragma unroll
                for (int r = 0; r < 16; ++r) {
                    const int rc = (r & 3) + 8 * (r >> 2) + 4 * h;
                    if (csub == 1) { if (rc > ql) s0[r] = -1e30f; }
                    else           { if (rc > ql) s1[r] = -1e30f; }
                }
            }

            // ---- row max: depth-5 tree + permlane cross-half ----
            float tm;
            {
                float t[8];
                if (csub > 1) {
                    #pragma unroll
                    for (int r = 0; r < 8; ++r)
                        t[r] = fmaxf(fmaxf(s0[2 * r], s0[2 * r + 1]),
                                     fmaxf(s1[2 * r], s1[2 * r + 1]));
                } else {
                    #pragma unroll
                    for (int r = 0; r < 8; ++r) t[r] = fmaxf(s0[2 * r], s0[2 * r + 1]);
                }
                t[0] = fmaxf(t[0], t[4]); t[1] = fmaxf(t[1], t[5]);
                t[2] = fmaxf(t[2], t[6]); t[3] = fmaxf(t[3], t[7]);
                t[0] = fmaxf(t[0], t[2]); t[1] = fmaxf(t[1], t[3]);
                tm = fmaxf(t[0], t[1]);
                float th;
                const float tl = xhalf_pair(tm, th);
                tm = fmaxf(tl, th);
            }

            // ---- defer-max rescale (T13, THR=8, log2 domain) ----
            if (!__all(tm <= mrun + 8.f)) {
                const float mnew = fmaxf(mrun, tm);
                const float fsc = exp2f(mrun - mnew);
                mrun = mnew;
                lrun *= fsc;
                #pragma unroll
                for (int r = 0; r < 16; ++r) {
                    const float f = __shfl(fsc, (r & 3) + 8 * (r >> 2) + 4 * h);
                    acc0[r] *= f; acc1[r] *= f;
                }
            }

            // ---- P = exp2(S - m); psum via depth-5 tree + permlane ----
            #pragma unroll
            for (int r = 0; r < 16; ++r) s0[r] = exp2f(s0[r] - mrun);
            if (csub > 1) {
                #pragma unroll
                for (int r = 0; r < 16; ++r) s1[r] = exp2f(s1[r] - mrun);
            }
            {
                float t[8];
                if (csub > 1) {
                    #pragma unroll
                    for (int r = 0; r < 8; ++r)
                        t[r] = (s0[2 * r] + s0[2 * r + 1]) + (s1[2 * r] + s1[2 * r + 1]);
                } else {
                    #pragma unroll
                    for (int r = 0; r < 8; ++r) t[r] = s0[2 * r] + s0[2 * r + 1];
                }
                t[0] += t[4]; t[1] += t[5]; t[2] += t[6]; t[3] += t[7];
                t[0] += t[2]; t[1] += t[3];
                float psum = t[0] + t[1];
                float ph;
                const float pl = xhalf_pair(psum, ph);
                lrun += pl + ph;
            }

            // ---- PA fragments in-register (T12) ----
            bf16x8 pa[4];
            #pragma unroll
            for (int a = 0; a < 2; ++a) {
                if (a < csub) {
                    #pragma unroll
                    for (int b = 0; b < 2; ++b) {
                        const f32x16& P = a ? s1 : s0;
                        unsigned w0 = cvtpk(P[8 * b + 0], P[8 * b + 1]);
                        unsigned w1 = cvtpk(P[8 * b + 2], P[8 * b + 3]);
                        unsigned w2 = cvtpk(P[8 * b + 4], P[8 * b + 5]);
                        unsigned w3 = cvtpk(P[8 * b + 6], P[8 * b + 7]);
                        PLSWAP(w0, w2);   // distinct registers: safe
                        PLSWAP(w1, w3);
                        unsigned wd[4] = {w0, w1, w2, w3};
                        pa[2 * a + b] = *(bf16x8*)wd;
                    }
                }
            }

            // ---- O += P V ----
            __builtin_amdgcn_s_setprio(1);
            #pragma unroll
            for (int ks = 0; ks < 4; ++ks) {
                if (ks < 2 * csub) {
                    const bf16x8 vf0 = *(const bf16x8*)&Vb[ql * 64 + ((ks * 2 + h) ^ (ql & 7)) * 8];
                    const bf16x8 vf1 = *(const bf16x8*)&Vb[(32 + ql) * 64 + ((ks * 2 + h) ^ (ql & 7)) * 8];
                    acc0 = __builtin_amdgcn_mfma_f32_32x32x16_bf16(pa[ks], vf0, acc0, 0, 0, 0);
                    acc1 = __builtin_amdgcn_mfma_f32_32x32x16_bf16(pa[ks], vf1, acc1, 0, 0, 0);
                }
            }
            __builtin_amdgcn_s_setprio(0);
        }
        __syncthreads();
        cur ^= 1;
    }

    // ---- epilogue: normalize, write bf16 [N*T, C] ----
    const float linv = 1.f / lrun;
    const int nn = nh >> 4, hh = nh & 15;
    #pragma unroll
    for (int r = 0; r < 16; ++r) {
        const int rc = (r & 3) + 8 * (r >> 2) + 4 * h;
        const float li = __shfl(linv, rc);
        const size_t rb = (size_t)(nn * T_ + qrow0 + rc) * C_ + hh * 64;
        ob[rb + ql]      = f2bf(acc0[r] * li);
        ob[rb + 32 + ql] = f2bf(acc1[r] * li);
    }
    #undef STAGE
}

// ---------------------------------------------------------------------------
extern "C" void kernel_launch(void* const* d_in, const int* in_sizes, int n_in,
                              void* d_out, int out_size, void* d_ws, size_t ws_size,
                              hipStream_t stream) {
    const float* x  = (const float*)d_in[0];
    const float* Wq = (const float*)d_in[1];
    const float* Wk = (const float*)d_in[2];
    const float* Wv = (const float*)d_in[3];
    const float* Wo = (const float*)d_in[4];
    const float* bo = (const float*)d_in[5];
    float* out = (float*)d_out;

    unsigned short* ws = (unsigned short*)d_ws;
    unsigned short* x_bf   = ws;                         // NTC
    unsigned short* w_bf   = x_bf + (size_t)NTC;         // 4*WELEM (contiguous after x_bf)
    unsigned short* qkv_bf = w_bf + (size_t)4 * WELEM;   // Q | K | V^T, NTC each
    unsigned short* a_bf   = qkv_bf + (size_t)3 * NTC;

    // one merged cast dispatch: x_bf | w_bf region is contiguous
    cast_all<<<(NTC + 4 * WELEM) / (8 * 256), 256, 0, stream>>>(x, Wq, Wk, Wv, Wo, x_bf);

    dim3 gq(N_ * T_ / 128, C_ / 128, 3);
    qkv_fused<<<gq, 256, 0, stream>>>(x_bf, w_bf, qkv_bf);

    attn_mfma<<<(T_ / 128) * (N_ * H_), 256, 0, stream>>>(
        qkv_bf, qkv_bf + (size_t)NTC, qkv_bf + (size_t)2 * NTC, a_bf);

    dim3 gg(N_ * T_ / 128, C_ / 128);
    out_gemm<<<gg, 256, 0, stream>>>(a_bf, w_bf + 3 * (size_t)WELEM, bo, out);
}

// Round 15
// 162.229 us; speedup vs baseline: 1.3740x; 1.0138x over previous
//
#include <hip/hip_runtime.h>
#include <math.h>

#define N_ 4
#define T_ 2048
#define C_ 1024
#define H_ 16
#define D_ 64
#define NTC (N_*T_*C_)   // 8388608
#define WELEM (C_*C_)    // 1048576

typedef float f32x4  __attribute__((ext_vector_type(4)));
typedef float f32x16 __attribute__((ext_vector_type(16)));
typedef short bf16x8 __attribute__((ext_vector_type(8)));

static __device__ __forceinline__ unsigned short f2bf(float f) {
    union { float f; unsigned u; } v; v.f = f;
    unsigned r = v.u + 0x7FFFu + ((v.u >> 16) & 1u);   // RNE
    return (unsigned short)(r >> 16);
}

static __device__ __forceinline__ unsigned cvtpk(float lo, float hi) {
    unsigned r;
    asm("v_cvt_pk_bf16_f32 %0, %1, %2" : "=v"(r) : "v"(lo), "v"(hi));
    return r;
}
// v_permlane32_swap_b32 a, b — ONLY on provably distinct registers (round-5 bug).
#define PLSWAP(a, b) asm("v_permlane32_swap_b32 %0, %1" : "+v"(a), "+v"(b))

// Cross-half exchange via permlane32_swap (VALU) instead of __shfl_xor(x,32)
// (ds_bpermute). The asm mov creates a value the compiler cannot coalesce
// with x (opaque), so the swap operands are distinct registers.
static __device__ __forceinline__ float xhalf_pair(float x, float& hiout) {
    float a = x, b;
    asm("v_mov_b32 %0, %1" : "=v"(b) : "v"(a));
    asm("v_permlane32_swap_b32 %0, %1" : "+v"(a), "+v"(b));
    hiout = b;
    return a;
}

#define GLDS16(gptr, lptr) \
    __builtin_amdgcn_global_load_lds((const __attribute__((address_space(1))) void*)(gptr), \
                                     (__attribute__((address_space(3))) void*)(lptr), 16, 0, 0)

// ---------------------------------------------------------------------------
// Merged fp32 -> bf16 cast: x (NTC elems) then Wq|Wk|Wv|Wo (4*WELEM) into the
// contiguous x_bf|w_bf workspace region. One dispatch, 8 elems/thread.
// ---------------------------------------------------------------------------
__global__ __launch_bounds__(256) void cast_all(const float* __restrict__ x,
                                                const float* __restrict__ w0,
                                                const float* __restrict__ w1,
                                                const float* __restrict__ w2,
                                                const float* __restrict__ w3,
                                                unsigned short* __restrict__ dst) {
    const int i = blockIdx.x * 256 + threadIdx.x;
    const size_t e = (size_t)i * 8;            // element offset into dst
    const float* __restrict__ src;
    size_t soff;
    if (e < (size_t)NTC) {
        src = x; soff = e;
    } else {
        const size_t e2 = e - (size_t)NTC;
        const int z = (int)(e2 >> 20);         // / WELEM
        src = (z == 0) ? w0 : (z == 1) ? w1 : (z == 2) ? w2 : w3;
        soff = e2 & (WELEM - 1);
    }
    const float4 a = *(const float4*)(src + soff);
    const float4 b = *(const float4*)(src + soff + 4);
    unsigned short u[8] = {f2bf(a.x), f2bf(a.y), f2bf(a.z), f2bf(a.w),
                           f2bf(b.x), f2bf(b.y), f2bf(b.z), f2bf(b.w)};
    *(uint4*)&dst[e] = *(const uint4*)u;
}

// ---------------------------------------------------------------------------
// Shared GEMM body — m97 structure with BK=64 (round-12 win: 2x MFMA work per
// vmcnt(0)-drain, LDS 32 KB, occupancy preserved; qkv at ~1150 TF).
// LDS swizzle: 8 chunks of 16B per row; LDS[row][p] = logical[row][p^(row&7)]
// (pre-swizzled global source; read applies same XOR — rule #21 involution).
// ---------------------------------------------------------------------------
#define GEMM_BODY(Aptr, Bptr)                                                           \
    __shared__ __align__(16) unsigned short Abuf[128 * 64];                             \
    __shared__ __align__(16) unsigned short Bbuf[128 * 64];                             \
    const int tid  = threadIdx.x;                                                       \
    const int lane = tid & 63;                                                          \
    const int w    = tid >> 6;                                                          \
    const int lo   = lane & 15;                                                         \
    const int hi   = lane >> 4;                                                         \
    const int wm   = w >> 1;                                                            \
    const int wn   = w & 1;                                                             \
    const int rowBase = blockIdx.x * 128;                                               \
    const int colBase = blockIdx.y * 128;                                               \
    f32x4 acc[4][4];                                                                    \
    _Pragma("unroll")                                                                   \
    for (int i = 0; i < 4; ++i)                                                         \
        _Pragma("unroll")                                                               \
        for (int j = 0; j < 4; ++j) acc[i][j] = (f32x4)(0.f);                           \
    const unsigned short* gA[4];                                                        \
    const unsigned short* gB[4];                                                        \
    _Pragma("unroll")                                                                   \
    for (int j = 0; j < 4; ++j) {                                                       \
        const int cj = tid + 256 * j;                                                   \
        const int rr = cj >> 3;                                                         \
        const int cc = ((cj & 7) ^ (rr & 7)) * 8;                                       \
        gA[j] = (Aptr) + (size_t)(rowBase + rr) * C_ + cc;                              \
        gB[j] = (Bptr) + (size_t)(colBase + rr) * C_ + cc;                              \
    }                                                                                   \
    for (int k0 = 0; k0 < C_; k0 += 64) {                                               \
        _Pragma("unroll")                                                               \
        for (int j = 0; j < 4; ++j)                                                     \
            GLDS16(gA[j] + k0, &Abuf[(tid + 256 * j) * 8]);                             \
        _Pragma("unroll")                                                               \
        for (int j = 0; j < 4; ++j)                                                     \
            GLDS16(gB[j] + k0, &Bbuf[(tid + 256 * j) * 8]);                             \
        __syncthreads();                                                                \
        _Pragma("unroll")                                                               \
        for (int kk = 0; kk < 2; ++kk) {                                                \
            bf16x8 af[4], bfv[4];                                                       \
            _Pragma("unroll")                                                           \
            for (int mi = 0; mi < 4; ++mi) {                                            \
                const int row = wm * 64 + mi * 16 + lo;                                 \
                const int p = ((kk * 4 + hi) ^ (row & 7)) * 8;                          \
                af[mi] = *(const bf16x8*)&Abuf[row * 64 + p];                           \
            }                                                                           \
            _Pragma("unroll")                                                           \
            for (int ni = 0; ni < 4; ++ni) {                                            \
                const int row = wn * 64 + ni * 16 + lo;                                 \
                const int p = ((kk * 4 + hi) ^ (row & 7)) * 8;                          \
                bfv[ni] = *(const bf16x8*)&Bbuf[row * 64 + p];                          \
            }                                                                           \
            _Pragma("unroll")                                                           \
            for (int mi = 0; mi < 4; ++mi)                                              \
                _Pragma("unroll")                                                       \
                for (int ni = 0; ni < 4; ++ni)                                          \
                    acc[mi][ni] = __builtin_amdgcn_mfma_f32_16x16x32_bf16(af[mi],       \
                                      bfv[ni], acc[mi][ni], 0, 0, 0);                   \
        }                                                                               \
        __syncthreads();                                                                \
    }

// ---------------------------------------------------------------------------
// Fused QKV projection: grid (64, 8, 3); z = 0:Q, 1:K (bf16 [NH,T,D]),
// 2: V^T (bf16 [NH*64+d][T]). Q pre-scaled by log2e/sqrt(C).
// ---------------------------------------------------------------------------
__global__ __launch_bounds__(256) void qkv_fused(const unsigned short* __restrict__ A,
                                                 const unsigned short* __restrict__ Wall,
                                                 unsigned short* __restrict__ qkvout) {
    const int z = blockIdx.z;
    const unsigned short* __restrict__ B = Wall + (size_t)z * WELEM;
    unsigned short* __restrict__ Y = qkvout + (size_t)z * NTC;
    const float oscale = (z == 0) ? (0.03125f * 1.44269504f) : 1.0f;

    GEMM_BODY(A, B)

    if (z < 2) {
        #pragma unroll
        for (int mi = 0; mi < 4; ++mi) {
            #pragma unroll
            for (int r = 0; r < 4; ++r) {
                const int row = rowBase + wm * 64 + mi * 16 + hi * 4 + r;
                const int nn = row >> 11, tt = row & (T_ - 1);
                #pragma unroll
                for (int ni = 0; ni < 4; ++ni) {
                    const int col = colBase + wn * 64 + ni * 16 + lo;
                    Y[((size_t)((nn * H_ + (col >> 6)) * T_ + tt)) * D_ + (col & 63)] =
                        f2bf(acc[mi][ni][r] * oscale);
                }
            }
        }
    } else {
        #pragma unroll
        for (int mi = 0; mi < 4; ++mi) {
            #pragma unroll
            for (int r = 0; r < 4; ++r) {
                const int row = rowBase + wm * 64 + mi * 16 + hi * 4 + r;
                const int nn = row >> 11, tt = row & (T_ - 1);
                #pragma unroll
                for (int ni = 0; ni < 4; ++ni) {
                    const int col = colBase + wn * 64 + ni * 16 + lo;
                    Y[(size_t)((nn * 16 + (col >> 6)) * 64 + (col & 63)) * T_ + tt] =
                        f2bf(acc[mi][ni][r]);
                }
            }
        }
    }
}

// ---------------------------------------------------------------------------
// Output projection: out = A @ Wo^T + bo (fp32 out).
// ---------------------------------------------------------------------------
__global__ __launch_bounds__(256) void out_gemm(const unsigned short* __restrict__ A,
                                                const unsigned short* __restrict__ B,
                                                const float* __restrict__ bo,
                                                float* __restrict__ out) {
    GEMM_BODY(A, B)

    float bias[4];
    #pragma unroll
    for (int ni = 0; ni < 4; ++ni) bias[ni] = bo[colBase + wn * 64 + ni * 16 + lo];
    #pragma unroll
    for (int mi = 0; mi < 4; ++mi) {
        #pragma unroll
        for (int r = 0; r < 4; ++r) {
            const int row = rowBase + wm * 64 + mi * 16 + hi * 4 + r;
            #pragma unroll
            for (int ni = 0; ni < 4; ++ni) {
                const int col = colBase + wn * 64 + ni * 16 + lo;
                out[(size_t)row * C_ + col] = acc[mi][ni][r] + bias[ni];
            }
        }
    }
}

// ---------------------------------------------------------------------------
// 32x32 MFMA flash attention — round-12/14 proven configuration plus one
// round-15 change: the softmax DENOMINATOR is computed on the MFMA pipe via
// the ones-column trick (acc_l = mfma(pa, ones, acc_l) -> acc_l[r] = l[q=rc]),
// replacing the per-tile ~32-op VALU psum tree + cross-half swap + the 16
// epilogue shfl broadcasts. Moves work from the 60%-busy VALU pipe to the
// 17%-utilized MFMA pipe; l now sums the same bf16-rounded P used in the
// numerator (consistent, error partially cancels in p/l).
// Core: (256,2), KVBLK=64, qtile-major longest-first, double-buffered
// K [k][64] + V^T [d][64k] via global_load_lds, XOR-pre-swizzled source
// (granule^(row&7)). mfma_f32_32x32x16_bf16 C/D: col=l&31,
// row=(r&3)+8*(r>>2)+4*(l>>5). Swapped QK^T (lane-local softmax), T12
// cvt_pk+permlane PA, T13 defer-max, depth-5 tree row-max.
// ---------------------------------------------------------------------------
__global__ __launch_bounds__(256, 2) void attn_mfma(const unsigned short* __restrict__ qg,
                                                    const unsigned short* __restrict__ kg,
                                                    const unsigned short* __restrict__ vtg,
                                                    unsigned short* __restrict__ ob) {
    __shared__ __align__(16) unsigned short Kt[2][64 * 64];
    __shared__ __align__(16) unsigned short Vt[2][64 * 64];

    const int tid  = threadIdx.x;
    const int w    = tid >> 6;
    const int lane = tid & 63;
    const int ql   = lane & 31;      // this lane's q-row (and d-col in PV)
    const int h    = lane >> 5;
    const int bid  = blockIdx.x;
    const int qtile = 15 - (bid >> 6);           // qtile-major, longest first
    const int nh   = bid & 63;
    const int qb   = qtile * 128;
    const size_t base  = (size_t)nh * (T_ * D_);
    const size_t vbase = (size_t)nh * 64 * T_;
    const int qrow0 = qb + w * 32;

    // Q B-fragments (held whole kernel); Q pre-scaled by log2e/sqrt(C).
    bf16x8 qf[4];
    #pragma unroll
    for (int dsl = 0; dsl < 4; ++dsl)
        qf[dsl] = *(const bf16x8*)(qg + base + (size_t)(qrow0 + ql) * D_ + dsl * 16 + h * 8);

    // all-ones bf16 B-fragment for the l-accumulation MFMA
    const unsigned ones2 = 0x3F803F80u;
    const unsigned od_[4] = {ones2, ones2, ones2, ones2};
    const bf16x8 vones = *(const bf16x8*)od_;

    f32x16 acc0 = (f32x16)(0.f), acc1 = (f32x16)(0.f);
    f32x16 acc_l = (f32x16)(0.f);     // acc_l[r] = l[q = rc] (denominator)
    float mrun = -INFINITY;

    const int mynkt  = (qrow0 >> 6) + 1;
    const int nktmax = (qb >> 6) + 2;
    const int csubdiag = (w & 1) + 1;

    // staging constants: thread handles 16B chunks i0, i1 of each tile
    const int i0 = tid, i1 = tid + 256;
    const int kr0 = i0 >> 3, kc0 = ((i0 & 7) ^ (kr0 & 7)) * 8;
    const int kr1 = i1 >> 3, kc1 = ((i1 & 7) ^ (kr1 & 7)) * 8;

    #define STAGE(kt_, buf_)                                                            \
        do {                                                                            \
            const int kb_ = (kt_) * 64;                                                 \
            GLDS16(kg + base + (size_t)(kb_ + kr0) * D_ + kc0, &Kt[buf_][i0 * 8]);      \
            GLDS16(kg + base + (size_t)(kb_ + kr1) * D_ + kc1, &Kt[buf_][i1 * 8]);      \
            GLDS16(vtg + vbase + (size_t)kr0 * T_ + kb_ + kc0, &Vt[buf_][i0 * 8]);      \
            GLDS16(vtg + vbase + (size_t)kr1 * T_ + kb_ + kc1, &Vt[buf_][i1 * 8]);      \
        } while (0)

    STAGE(0, 0);
    __syncthreads();
    int cur = 0;

    for (int kt = 0; kt < nktmax; ++kt) {
        if (kt + 1 < nktmax) STAGE(kt + 1, cur ^ 1);

        if (kt < mynkt) {
            const bool diag = (kt == mynkt - 1);
            const int csub = diag ? csubdiag : 2;
            const unsigned short* Kb = Kt[cur];
            const unsigned short* Vb = Vt[cur];

            // ---- S^T = K * Q^T ----
            f32x16 s0, s1;
            __builtin_amdgcn_s_setprio(1);
            {
                f32x16 z = (f32x16)(0.f);
                #pragma unroll
                for (int dsl = 0; dsl < 4; ++dsl) {
                    const bf16x8 ka = *(const bf16x8*)&Kb[ql * 64 + ((dsl * 2 + h) ^ (ql & 7)) * 8];
                    z = __builtin_amdgcn_mfma_f32_32x32x16_bf16(ka, qf[dsl], z, 0, 0, 0);
                }
                s0 = z;
            }
            if (csub > 1) {
                f32x16 z = (f32x16)(0.f);
                #pragma unroll
                for (int dsl = 0; dsl < 4; ++dsl) {
                    const bf16x8 ka = *(const bf16x8*)&Kb[(32 + ql) * 64 + ((dsl * 2 + h) ^ (ql & 7)) * 8];
                    z = __builtin_amdgcn_mfma_f32_32x32x16_bf16(ka, qf[dsl], z, 0, 0, 0);
                }
                s1 = z;
            }
            __builtin_amdgcn_s_setprio(0);

            // ---- causal mask (diag tile: mask last computed subtile) ----
            if (diag) {
                #pragma unroll
                for (int r = 0; r < 16; ++r) {
                    const int rc = (r & 3) + 8 * (r >> 2) + 4 * h;
                    if (csub == 1) { if (rc > ql) s0[r] = -1e30f; }
                    else           { if (rc > ql) s1[r] = -1e30f; }
                }
            }

            // ---- row max: depth-5 tree + permlane cross-half ----
            float tm;
            {
                float t[8];
                if (csub > 1) {
                    #pragma unroll
                    for (int r = 0; r < 8; ++r)
                        t[r] = fmaxf(fmaxf(s0[2 * r], s0[2 * r + 1]),
                                     fmaxf(s1[2 * r], s1[2 * r + 1]));
                } else {
                    #pragma unroll
                    for (int r = 0; r < 8; ++r) t[r] = fmaxf(s0[2 * r], s0[2 * r + 1]);
                }
                t[0] = fmaxf(t[0], t[4]); t[1] = fmaxf(t[1], t[5]);
                t[2] = fmaxf(t[2], t[6]); t[3] = fmaxf(t[3], t[7]);
                t[0] = fmaxf(t[0], t[2]); t[1] = fmaxf(t[1], t[3]);
                tm = fmaxf(t[0], t[1]);
                float th;
                const float tl = xhalf_pair(tm, th);
                tm = fmaxf(tl, th);
            }

            // ---- defer-max rescale (T13, THR=8, log2 domain) ----
            if (!__all(tm <= mrun + 8.f)) {
                const float mnew = fmaxf(mrun, tm);
                const float fsc = exp2f(mrun - mnew);
                mrun = mnew;
                #pragma unroll
                for (int r = 0; r < 16; ++r) {
                    const float f = __shfl(fsc, (r & 3) + 8 * (r >> 2) + 4 * h);
                    acc0[r] *= f; acc1[r] *= f; acc_l[r] *= f;
                }
            }

            // ---- P = exp2(S - m)  (psum now via MFMA ones-column below) ----
            #pragma unroll
            for (int r = 0; r < 16; ++r) s0[r] = exp2f(s0[r] - mrun);
            if (csub > 1) {
                #pragma unroll
                for (int r = 0; r < 16; ++r) s1[r] = exp2f(s1[r] - mrun);
            }

            // ---- PA fragments in-register (T12) ----
            bf16x8 pa[4];
            #pragma unroll
            for (int a = 0; a < 2; ++a) {
                if (a < csub) {
                    #pragma unroll
                    for (int b = 0; b < 2; ++b) {
                        const f32x16& P = a ? s1 : s0;
                        unsigned w0 = cvtpk(P[8 * b + 0], P[8 * b + 1]);
                        unsigned w1 = cvtpk(P[8 * b + 2], P[8 * b + 3]);
                        unsigned w2 = cvtpk(P[8 * b + 4], P[8 * b + 5]);
                        unsigned w3 = cvtpk(P[8 * b + 6], P[8 * b + 7]);
                        PLSWAP(w0, w2);   // distinct registers: safe
                        PLSWAP(w1, w3);
                        unsigned wd[4] = {w0, w1, w2, w3};
                        pa[2 * a + b] = *(bf16x8*)wd;
                    }
                }
            }

            // ---- O += P V ;  l += P * ones (denominator on MFMA pipe) ----
            __builtin_amdgcn_s_setprio(1);
            #pragma unroll
            for (int ks = 0; ks < 4; ++ks) {
                if (ks < 2 * csub) {
                    const bf16x8 vf0 = *(const bf16x8*)&Vb[ql * 64 + ((ks * 2 + h) ^ (ql & 7)) * 8];
                    const bf16x8 vf1 = *(const bf16x8*)&Vb[(32 + ql) * 64 + ((ks * 2 + h) ^ (ql & 7)) * 8];
                    acc0  = __builtin_amdgcn_mfma_f32_32x32x16_bf16(pa[ks], vf0, acc0, 0, 0, 0);
                    acc1  = __builtin_amdgcn_mfma_f32_32x32x16_bf16(pa[ks], vf1, acc1, 0, 0, 0);
                    acc_l = __builtin_amdgcn_mfma_f32_32x32x16_bf16(pa[ks], vones, acc_l, 0, 0, 0);
                }
            }
            __builtin_amdgcn_s_setprio(0);
        }
        __syncthreads();
        cur ^= 1;
    }

    // ---- epilogue: normalize (acc_l[r] = l[q=rc], no shfl), write bf16 ----
    const int nn = nh >> 4, hh = nh & 15;
    #pragma unroll
    for (int r = 0; r < 16; ++r) {
        const int rc = (r & 3) + 8 * (r >> 2) + 4 * h;
        const float li = 1.f / acc_l[r];
        const size_t rb = (size_t)(nn * T_ + qrow0 + rc) * C_ + hh * 64;
        ob[rb + ql]      = f2bf(acc0[r] * li);
        ob[rb + 32 + ql] = f2bf(acc1[r] * li);
    }
    #undef STAGE
}

// ---------------------------------------------------------------------------
extern "C" void kernel_launch(void* const* d_in, const int* in_sizes, int n_in,
                              void* d_out, int out_size, void* d_ws, size_t ws_size,
                              hipStream_t stream) {
    const float* x  = (const float*)d_in[0];
    const float* Wq = (const float*)d_in[1];
    const float* Wk = (const float*)d_in[2];
    const float* Wv = (const float*)d_in[3];
    const float* Wo = (const float*)d_in[4];
    const float* bo = (const float*)d_in[5];
    float* out = (float*)d_out;

    unsigned short* ws = (unsigned short*)d_ws;
    unsigned short* x_bf   = ws;                         // NTC
    unsigned short* w_bf   = x_bf + (size_t)NTC;         // 4*WELEM (contiguous after x_bf)
    unsigned short* qkv_bf = w_bf + (size_t)4 * WELEM;   // Q | K | V^T, NTC each
    unsigned short* a_bf   = qkv_bf + (size_t)3 * NTC;

    // one merged cast dispatch: x_bf | w_bf region is contiguous
    cast_all<<<(NTC + 4 * WELEM) / (8 * 256), 256, 0, stream>>>(x, Wq, Wk, Wv, Wo, x_bf);

    dim3 gq(N_ * T_ / 128, C_ / 128, 3);
    qkv_fused<<<gq, 256, 0, stream>>>(x_bf, w_bf, qkv_bf);

    attn_mfma<<<(T_ / 128) * (N_ * H_), 256, 0, stream>>>(
        qkv_bf, qkv_bf + (size_t)NTC, qkv_bf + (size_t)2 * NTC, a_bf);

    dim3 gg(N_ * T_ / 128, C_ / 128);
    out_gemm<<<gg, 256, 0, stream>>>(a_bf, w_bf + 3 * (size_t)WELEM, bo, out);
}